// Round 1
// baseline (59645.831 us; speedup 1.0000x reference)
//
#include <hip/hip_runtime.h>
#include <hip/hip_bf16.h>
#include <math.h>

#define B_    512
#define T_    128
#define DET_  512
#define STOCH_ 32
#define EMB_  1024
#define ACTD_ 6
#define HID_  512

// output slice offsets (floats)
#define OFF_STOCH 33554432u
#define OFF_PM    35651584u
#define OFF_PS    37748736u
#define OFF_QM    39845888u
#define OFF_QS    41943040u

__device__ __forceinline__ float sigm(float x) { return 1.f / (1.f + __expf(-x)); }
__device__ __forceinline__ float softplusf(float x) {
    return fmaxf(x, 0.f) + log1pf(__expf(-fabsf(x)));
}
__device__ __forceinline__ float eluf(float x) { return (x > 0.f) ? x : (__expf(x) - 1.f); }

__device__ __forceinline__ void ld_bf16x4(const __hip_bfloat16* p, float& a, float& b,
                                          float& c, float& d) {
    const __hip_bfloat162* p2 = (const __hip_bfloat162*)p;
    float2 u = __bfloat1622float2(p2[0]);
    float2 v = __bfloat1622float2(p2[1]);
    a = u.x; b = u.y; c = v.x; d = v.y;
}

// ---------------------------------------------------------------------------
// Kernel 1: fused GRU step.  h_t written to det slice.
// Tile: 32 batch rows x 32 h-cols (x3 gates). grid (16,16), 256 threads.
// ---------------------------------------------------------------------------
__global__ __launch_bounds__(256) void k_gru(
    float* __restrict__ det, const float* __restrict__ stoch,
    const float* __restrict__ actions,
    const float* __restrict__ wih, const float* __restrict__ whh,
    const float* __restrict__ bih, const float* __restrict__ bhh, int t)
{
    __shared__ float hs[32][36];   // h chunk
    __shared__ float wsh[96][36];  // whh rows for r,z,n cols of this tile
    __shared__ float ss[32][36];   // s (stoch) rows
    __shared__ float aa[32][8];    // action rows
    __shared__ float wx[96][40];   // wih rows (38 cols)

    const int tid = threadIdx.x;
    const int j = tid & 31, r = tid >> 5;
    const int col0 = blockIdx.x * 32;
    const int b0   = blockIdx.y * 32;

    float accR[4] = {0,0,0,0}, accZ[4] = {0,0,0,0};
    float accNx[4] = {0,0,0,0}, accNh[4] = {0,0,0,0};

    if (t > 0) {
        for (int kc = 0; kc < 16; ++kc) {
            const int k0 = kc * 32;
            #pragma unroll
            for (int i2 = 0; i2 < 4; ++i2) {
                int row = r + 8 * i2;
                hs[row][j] = det[((size_t)(b0 + row) * T_ + (t - 1)) * DET_ + k0 + j];
            }
            #pragma unroll
            for (int i2 = 0; i2 < 12; ++i2) {
                int row96 = r + 8 * i2;
                int g = row96 >> 5, jj = row96 & 31;
                wsh[row96][j] = whh[(size_t)(g * DET_ + col0 + jj) * DET_ + k0 + j];
            }
            __syncthreads();
            #pragma unroll
            for (int kk = 0; kk < 32; kk += 4) {
                float4 wr = *(const float4*)&wsh[j][kk];
                float4 wz = *(const float4*)&wsh[32 + j][kk];
                float4 wn = *(const float4*)&wsh[64 + j][kk];
                #pragma unroll
                for (int i = 0; i < 4; ++i) {
                    float4 hv = *(const float4*)&hs[r + 8 * i][kk];
                    accR[i]  += hv.x * wr.x + hv.y * wr.y + hv.z * wr.z + hv.w * wr.w;
                    accZ[i]  += hv.x * wz.x + hv.y * wz.y + hv.z * wz.z + hv.w * wz.w;
                    accNh[i] += hv.x * wn.x + hv.y * wn.y + hv.z * wn.z + hv.w * wn.w;
                }
            }
            __syncthreads();
        }
    }

    // --- gx part: K = 32 (s) + 6 (a) ---
    if (t > 0) {
        #pragma unroll
        for (int i2 = 0; i2 < 4; ++i2) {
            int row = r + 8 * i2;
            ss[row][j] = stoch[((size_t)(b0 + row) * T_ + (t - 1)) * STOCH_ + j];
        }
    }
    if (tid < 192) {
        int row = tid / 6, k = tid - row * 6;
        aa[row][k] = actions[((size_t)(b0 + row) * T_ + t) * ACTD_ + k];
    }
    for (int idx = tid; idx < 96 * 38; idx += 256) {
        int row96 = idx / 38, k = idx - row96 * 38;
        int g = row96 >> 5, jj = row96 & 31;
        wx[row96][k] = wih[(size_t)(g * DET_ + col0 + jj) * 38 + k];
    }
    __syncthreads();

    #pragma unroll
    for (int i = 0; i < 4; ++i) {
        int row = r + 8 * i;
        if (t > 0) {
            for (int k = 0; k < 32; ++k) {
                float sv = ss[row][k];
                accR[i]  += sv * wx[j][k];
                accZ[i]  += sv * wx[32 + j][k];
                accNx[i] += sv * wx[64 + j][k];
            }
        }
        #pragma unroll
        for (int k = 0; k < 6; ++k) {
            float av = aa[row][k];
            accR[i]  += av * wx[j][32 + k];
            accZ[i]  += av * wx[32 + j][32 + k];
            accNx[i] += av * wx[64 + j][32 + k];
        }
    }

    const int jg = col0 + j;
    const float br  = bih[jg] + bhh[jg];
    const float bz  = bih[DET_ + jg] + bhh[DET_ + jg];
    const float bnx = bih[2 * DET_ + jg];
    const float bnh = bhh[2 * DET_ + jg];
    #pragma unroll
    for (int i = 0; i < 4; ++i) {
        int bg = b0 + r + 8 * i;
        float rv = sigm(accR[i] + br);
        float zv = sigm(accZ[i] + bz);
        float nv = tanhf(accNx[i] + bnx + rv * (accNh[i] + bnh));
        float hp = (t > 0) ? det[((size_t)bg * T_ + (t - 1)) * DET_ + jg] : 0.f;
        det[((size_t)bg * T_ + t) * DET_ + jg] = (1.f - zv) * nv + zv * hp;
    }
}

// ---------------------------------------------------------------------------
// Kernel 2: representation MLP layer 1.  q1 = ELU([h_t, e_t] @ rep_w1.T + b1)
// Tile 32x32, grid (16,16). q1 scratch = pm output slice.
// ---------------------------------------------------------------------------
__global__ __launch_bounds__(256) void k_rep1(
    const float* __restrict__ det, const float* __restrict__ emb,
    const float* __restrict__ rw1, const float* __restrict__ rb1,
    float* __restrict__ q1, int t)
{
    __shared__ float at[32][36];
    __shared__ float wt[32][36];
    const int tid = threadIdx.x;
    const int j = tid & 31, r = tid >> 5;
    const int i0 = blockIdx.x * 32;
    const int b0 = blockIdx.y * 32;
    float acc[4] = {0,0,0,0};

    // phase 1: h part (K=512)
    for (int kc = 0; kc < 16; ++kc) {
        const int k0 = kc * 32;
        #pragma unroll
        for (int i2 = 0; i2 < 4; ++i2) {
            int row = r + 8 * i2;
            at[row][j] = det[((size_t)(b0 + row) * T_ + t) * DET_ + k0 + j];
            wt[row][j] = rw1[(size_t)(i0 + row) * 1536 + k0 + j];
        }
        __syncthreads();
        #pragma unroll
        for (int kk = 0; kk < 32; kk += 4) {
            float4 wv = *(const float4*)&wt[j][kk];
            #pragma unroll
            for (int i = 0; i < 4; ++i) {
                float4 av = *(const float4*)&at[r + 8 * i][kk];
                acc[i] += av.x * wv.x + av.y * wv.y + av.z * wv.z + av.w * wv.w;
            }
        }
        __syncthreads();
    }
    // phase 2: e part (K=1024)
    for (int kc = 0; kc < 32; ++kc) {
        const int k0 = kc * 32;
        #pragma unroll
        for (int i2 = 0; i2 < 4; ++i2) {
            int row = r + 8 * i2;
            at[row][j] = emb[((size_t)(b0 + row) * T_ + t) * EMB_ + k0 + j];
            wt[row][j] = rw1[(size_t)(i0 + row) * 1536 + 512 + k0 + j];
        }
        __syncthreads();
        #pragma unroll
        for (int kk = 0; kk < 32; kk += 4) {
            float4 wv = *(const float4*)&wt[j][kk];
            #pragma unroll
            for (int i = 0; i < 4; ++i) {
                float4 av = *(const float4*)&at[r + 8 * i][kk];
                acc[i] += av.x * wv.x + av.y * wv.y + av.z * wv.z + av.w * wv.w;
            }
        }
        __syncthreads();
    }

    const int ig = i0 + j;
    #pragma unroll
    for (int i = 0; i < 4; ++i) {
        int bg = b0 + r + 8 * i;
        q1[(size_t)bg * HID_ + ig] = eluf(acc[i] + rb1[ig]);
    }
}

// ---------------------------------------------------------------------------
// Kernel 3: rep layer 2 + dist params + rsample.  32 rows x 64 cols, grid 16.
// ---------------------------------------------------------------------------
__global__ __launch_bounds__(256) void k_rep2(
    const float* __restrict__ q1, const float* __restrict__ rw2,
    const float* __restrict__ rb2, const float* __restrict__ noise,
    float* __restrict__ stoch, float* __restrict__ qm, float* __restrict__ qsd, int t)
{
    __shared__ float qt[32][36];
    __shared__ float w2s[64][36];
    __shared__ float o2[32][68];
    const int tid = threadIdx.x;
    const int o = tid & 63, rg = tid >> 6;
    const int kk = tid & 31, rr = tid >> 5;
    const int b0 = blockIdx.x * 32;
    float acc[8] = {0,0,0,0,0,0,0,0};

    for (int kc = 0; kc < 16; ++kc) {
        const int k0 = kc * 32;
        #pragma unroll
        for (int i2 = 0; i2 < 4; ++i2)
            qt[rr + 8 * i2][kk] = q1[(size_t)(b0 + rr + 8 * i2) * HID_ + k0 + kk];
        #pragma unroll
        for (int i2 = 0; i2 < 8; ++i2)
            w2s[rr + 8 * i2][kk] = rw2[(size_t)(rr + 8 * i2) * HID_ + k0 + kk];
        __syncthreads();
        #pragma unroll
        for (int k4 = 0; k4 < 32; k4 += 4) {
            float4 wv = *(const float4*)&w2s[o][k4];
            #pragma unroll
            for (int i = 0; i < 8; ++i) {
                float4 qv = *(const float4*)&qt[rg + 4 * i][k4];
                acc[i] += qv.x * wv.x + qv.y * wv.y + qv.z * wv.z + qv.w * wv.w;
            }
        }
        __syncthreads();
    }
    #pragma unroll
    for (int i = 0; i < 8; ++i) o2[rg + 4 * i][o] = acc[i] + rb2[o];
    __syncthreads();
    if (o < 32) {
        #pragma unroll
        for (int i = 0; i < 8; ++i) {
            int bl = rg + 4 * i;
            int bg = b0 + bl;
            float m  = o2[bl][o];
            float sd = softplusf(o2[bl][o + 32]) + 0.1f;
            size_t oi = ((size_t)bg * T_ + t) * STOCH_ + o;
            qm[oi]    = m;
            qsd[oi]   = sd;
            stoch[oi] = m + sd * noise[oi];
        }
    }
}

// ---------------------------------------------------------------------------
// Kernel 4: deferred transition MLP over all B*T rows.  16 rows/WG, grid 4096.
// t1 hidden kept in LDS as bf16 (tolerance is 0.365 absmax — far above bf16 err).
// ---------------------------------------------------------------------------
__global__ __launch_bounds__(256) void k_trans(
    const float* __restrict__ det,
    const float* __restrict__ tw1, const float* __restrict__ tb1,
    const float* __restrict__ tw2, const float* __restrict__ tb2,
    float* __restrict__ pm, float* __restrict__ ps)
{
    __shared__ __hip_bfloat16 act[16][520];
    __shared__ __hip_bfloat16 t1h[16][520];
    __shared__ float wt[64][68];

    const int tid = threadIdx.x;
    const int row0 = blockIdx.x * 16;
    const int jc = tid & 63, rg = tid >> 6;

    for (int idx = tid; idx < 16 * 512; idx += 256) {
        int row = idx >> 9, k = idx & 511;
        act[row][k] = __float2bfloat16(det[(size_t)(row0 + row) * 512 + k]);
    }

    // layer 1: 8 col-tiles of 64, K=512 in chunks of 64
    for (int c = 0; c < 8; ++c) {
        float acc[4] = {0,0,0,0};
        for (int kc = 0; kc < 8; ++kc) {
            const int k0 = kc * 64;
            __syncthreads();
            for (int idx = tid; idx < 64 * 64; idx += 256) {
                int row = idx >> 6, k = idx & 63;
                wt[row][k] = tw1[(size_t)(c * 64 + row) * 512 + k0 + k];
            }
            __syncthreads();
            for (int k = 0; k < 64; k += 4) {
                float4 wv = *(const float4*)&wt[jc][k];
                #pragma unroll
                for (int i = 0; i < 4; ++i) {
                    float a0, a1, a2, a3;
                    ld_bf16x4(&act[rg + 4 * i][k0 + k], a0, a1, a2, a3);
                    acc[i] += a0 * wv.x + a1 * wv.y + a2 * wv.z + a3 * wv.w;
                }
            }
        }
        #pragma unroll
        for (int i = 0; i < 4; ++i)
            t1h[rg + 4 * i][c * 64 + jc] = __float2bfloat16(eluf(acc[i] + tb1[c * 64 + jc]));
    }

    // layer 2: 64 outputs, K=512
    float acc2[4] = {0,0,0,0};
    for (int kc = 0; kc < 8; ++kc) {
        const int k0 = kc * 64;
        __syncthreads();
        for (int idx = tid; idx < 64 * 64; idx += 256) {
            int row = idx >> 6, k = idx & 63;
            wt[row][k] = tw2[(size_t)row * 512 + k0 + k];
        }
        __syncthreads();
        for (int k = 0; k < 64; k += 4) {
            float4 wv = *(const float4*)&wt[jc][k];
            #pragma unroll
            for (int i = 0; i < 4; ++i) {
                float a0, a1, a2, a3;
                ld_bf16x4(&t1h[rg + 4 * i][k0 + k], a0, a1, a2, a3);
                acc2[i] += a0 * wv.x + a1 * wv.y + a2 * wv.z + a3 * wv.w;
            }
        }
    }
    #pragma unroll
    for (int i = 0; i < 4; ++i) {
        size_t rgl = (size_t)row0 + rg + 4 * i;
        float v = acc2[i] + tb2[jc];
        if (jc < 32) pm[rgl * 32 + jc] = v;
        else         ps[rgl * 32 + (jc - 32)] = softplusf(v) + 0.1f;
    }
}

// ---------------------------------------------------------------------------
extern "C" void kernel_launch(void* const* d_in, const int* in_sizes, int n_in,
                              void* d_out, int out_size, void* d_ws, size_t ws_size,
                              hipStream_t stream) {
    const float* emb   = (const float*)d_in[0];
    const float* acts  = (const float*)d_in[1];
    const float* noise = (const float*)d_in[2];
    const float* wih   = (const float*)d_in[3];
    const float* whh   = (const float*)d_in[4];
    const float* bih   = (const float*)d_in[5];
    const float* bhh   = (const float*)d_in[6];
    const float* tw1   = (const float*)d_in[7];
    const float* tb1   = (const float*)d_in[8];
    const float* tw2   = (const float*)d_in[9];
    const float* tb2   = (const float*)d_in[10];
    const float* rw1   = (const float*)d_in[11];
    const float* rb1   = (const float*)d_in[12];
    const float* rw2   = (const float*)d_in[13];
    const float* rb2   = (const float*)d_in[14];

    float* out   = (float*)d_out;
    float* det   = out;
    float* stoch = out + OFF_STOCH;
    float* pm    = out + OFF_PM;
    float* ps    = out + OFF_PS;
    float* qm    = out + OFF_QM;
    float* qsd   = out + OFF_QS;
    float* q1    = pm;  // scratch during the scan; trans overwrites pm afterwards

    for (int t = 0; t < T_; ++t) {
        k_gru<<<dim3(16, 16), 256, 0, stream>>>(det, stoch, acts, wih, whh, bih, bhh, t);
        k_rep1<<<dim3(16, 16), 256, 0, stream>>>(det, emb, rw1, rb1, q1, t);
        k_rep2<<<dim3(16), 256, 0, stream>>>(q1, rw2, rb2, noise, stoch, qm, qsd, t);
    }
    k_trans<<<dim3(4096), 256, 0, stream>>>(det, tw1, tb1, tw2, tb2, pm, ps);
}

// Round 2
// 27258.002 us; speedup vs baseline: 2.1882x; 2.1882x over previous
//
#include <hip/hip_runtime.h>
#include <hip/hip_bf16.h>
#include <math.h>

#define B_    512
#define T_    128
#define DET_  512
#define STOCH_ 32
#define EMB_  1024
#define ACTD_ 6
#define HID_  512

// output slice offsets (floats)
#define OFF_STOCH 33554432u
#define OFF_PM    35651584u
#define OFF_PS    37748736u
#define OFF_QM    39845888u
#define OFF_QS    41943040u

typedef short bhalf8 __attribute__((ext_vector_type(8)));
typedef float f32x4  __attribute__((ext_vector_type(4)));

__device__ __forceinline__ float sigm(float x) { return 1.f / (1.f + __expf(-x)); }
__device__ __forceinline__ float softplusf(float x) {
    return fmaxf(x, 0.f) + log1pf(__expf(-fabsf(x)));
}
__device__ __forceinline__ float eluf(float x) { return (x > 0.f) ? x : (__expf(x) - 1.f); }
__device__ __forceinline__ float tanh_fast(float x) {
    return 1.f - 2.f / (__expf(2.f * x) + 1.f);   // +inf -> 1, -inf -> -1
}
__device__ __forceinline__ short f2bf(float f) {
    __hip_bfloat16 h = __float2bfloat16(f);
    return *reinterpret_cast<short*>(&h);
}
__device__ __forceinline__ void ld_bf16x4(const __hip_bfloat16* p, float& a, float& b,
                                          float& c, float& d) {
    const __hip_bfloat162* p2 = (const __hip_bfloat162*)p;
    float2 u = __bfloat1622float2(p2[0]);
    float2 v = __bfloat1622float2(p2[1]);
    a = u.x; b = u.y; c = v.x; d = v.y;
}

// ---------------------------------------------------------------------------
// Prep: convert weights to bf16 into the ps output slice (scratch until trans).
//   WBIG [2048][576]: rows 0..511 r-gate [wih_r|whh_r], 512..1023 z,
//                     1024..1535 hn [0|whh_n], 1536..2047 xn [wih_n|0]
//   K layout: k<64 = [s(32), a(6), 0(26)], k>=64 = h(512)
// ---------------------------------------------------------------------------
__global__ __launch_bounds__(256) void k_prep(
    const float* __restrict__ wih, const float* __restrict__ whh,
    const float* __restrict__ rw1, const float* __restrict__ rw2,
    short* __restrict__ WBIG, short* __restrict__ RW1b, short* __restrict__ RW2b)
{
    const int idx = blockIdx.x * 256 + threadIdx.x;
    const int stride = gridDim.x * 256;
    for (int i = idx; i < 2048 * 576; i += stride) {
        int n = i / 576, k = i - n * 576;
        float v = 0.f;
        if (k < 64) {
            if (k < 38) {
                if (n < 1024)       v = wih[n * 38 + k];
                else if (n >= 1536) v = wih[(n - 512) * 38 + k];
            }
        } else {
            if (n < 1536) v = whh[(size_t)n * 512 + (k - 64)];
        }
        WBIG[i] = f2bf(v);
    }
    for (int i = idx; i < 512 * 1536; i += stride) RW1b[i] = f2bf(rw1[i]);
    for (int i = idx; i < 64 * 512; i += stride)   RW2b[i] = f2bf(rw2[i]);
}

// ---------------------------------------------------------------------------
// GRU GEMM: G[512][2048] = A[512][576] @ WBIG.T, bf16 MFMA 16x16x32.
// WG = 256 thr = 4 waves (2x2), tile 64(M) x 64(N), BK=64. grid (32,8).
// ---------------------------------------------------------------------------
__global__ __launch_bounds__(256) void k_gemm_gru(
    const float* __restrict__ det, const float* __restrict__ stoch,
    const float* __restrict__ actions, const short* __restrict__ WBIG,
    float* __restrict__ G, int t)
{
    __shared__ __align__(16) short As[64][72];
    __shared__ __align__(16) short Bs[64][72];

    const int tid = threadIdx.x;
    const int lane = tid & 63, wave = tid >> 6;
    const int wm = wave & 1, wn = wave >> 1;
    const int q = lane >> 4, m16 = lane & 15;
    const int n0 = blockIdx.x * 64, b0 = blockIdx.y * 64;

    f32x4 acc[2][2] = {{{0,0,0,0},{0,0,0,0}},{{0,0,0,0},{0,0,0,0}}};

    const int nCh = (t == 0 || n0 >= 1536) ? 1 : 9;
    const int sr = tid >> 2, sc = (tid & 3) * 16;   // staging: 4 thr/row, 16 cols each

    for (int kc = 0; kc < nCh; ++kc) {
        // ---- stage A (fp32 -> bf16) ----
        {
            const int b = b0 + sr;
            short tmp[16] __attribute__((aligned(16)));
            if (kc == 0) {
                #pragma unroll
                for (int c = 0; c < 16; ++c) {
                    int k = sc + c; float x = 0.f;
                    if (k < 32) { if (t > 0) x = stoch[((size_t)b * T_ + (t - 1)) * STOCH_ + k]; }
                    else if (k < 38) x = actions[((size_t)b * T_ + t) * ACTD_ + (k - 32)];
                    tmp[c] = f2bf(x);
                }
            } else {
                const float* src = det + ((size_t)b * T_ + (t - 1)) * DET_ + (kc - 1) * 64 + sc;
                #pragma unroll
                for (int v4 = 0; v4 < 4; ++v4) {
                    float4 f = ((const float4*)src)[v4];
                    tmp[v4 * 4 + 0] = f2bf(f.x); tmp[v4 * 4 + 1] = f2bf(f.y);
                    tmp[v4 * 4 + 2] = f2bf(f.z); tmp[v4 * 4 + 3] = f2bf(f.w);
                }
            }
            *(bhalf8*)&As[sr][sc]     = *(bhalf8*)&tmp[0];
            *(bhalf8*)&As[sr][sc + 8] = *(bhalf8*)&tmp[8];
        }
        // ---- stage B (prepped bf16) ----
        {
            const short* src = WBIG + (size_t)(n0 + sr) * 576 + kc * 64 + sc;
            *(bhalf8*)&Bs[sr][sc] = *(const bhalf8*)src;
            *(bhalf8*)&Bs[sr][sc + 8] = *(const bhalf8*)(src + 8);
        }
        __syncthreads();
        #pragma unroll
        for (int kk = 0; kk < 64; kk += 32) {
            bhalf8 av[2], bv[2];
            #pragma unroll
            for (int mi = 0; mi < 2; ++mi)
                av[mi] = *(const bhalf8*)&As[wm * 32 + mi * 16 + m16][kk + q * 8];
            #pragma unroll
            for (int ni = 0; ni < 2; ++ni)
                bv[ni] = *(const bhalf8*)&Bs[wn * 32 + ni * 16 + m16][kk + q * 8];
            #pragma unroll
            for (int mi = 0; mi < 2; ++mi)
                #pragma unroll
                for (int ni = 0; ni < 2; ++ni)
                    acc[mi][ni] = __builtin_amdgcn_mfma_f32_16x16x32_bf16(
                        av[mi], bv[ni], acc[mi][ni], 0, 0, 0);
        }
        __syncthreads();
    }
    // epilogue: C/D layout col=lane&15, row=q*4+reg
    #pragma unroll
    for (int mi = 0; mi < 2; ++mi)
        #pragma unroll
        for (int ni = 0; ni < 2; ++ni)
            #pragma unroll
            for (int r = 0; r < 4; ++r) {
                int row = wm * 32 + mi * 16 + q * 4 + r;
                int col = wn * 32 + ni * 16 + m16;
                G[(size_t)(b0 + row) * 2048 + n0 + col] = acc[mi][ni][r];
            }
}

// ---------------------------------------------------------------------------
// Gate epilogue: h_t from G + biases. 256 WGs x 256 thr x 4 cols.
// ---------------------------------------------------------------------------
__global__ __launch_bounds__(256) void k_gate(
    const float* __restrict__ G, const float* __restrict__ bih,
    const float* __restrict__ bhh, float* __restrict__ det, int t)
{
    const int flat = blockIdx.x * 256 + threadIdx.x;
    const int b = flat >> 7;
    const int j0 = (flat & 127) * 4;

    float4 gr  = *(const float4*)&G[(size_t)b * 2048 + j0];
    float4 gz  = *(const float4*)&G[(size_t)b * 2048 + 512 + j0];
    float4 ghn = *(const float4*)&G[(size_t)b * 2048 + 1024 + j0];
    float4 gxn = *(const float4*)&G[(size_t)b * 2048 + 1536 + j0];
    float4 br1 = *(const float4*)&bih[j0];
    float4 br2 = *(const float4*)&bhh[j0];
    float4 bz1 = *(const float4*)&bih[512 + j0];
    float4 bz2 = *(const float4*)&bhh[512 + j0];
    float4 bn1 = *(const float4*)&bih[1024 + j0];
    float4 bn2 = *(const float4*)&bhh[1024 + j0];
    float4 hp = {0, 0, 0, 0};
    if (t > 0) hp = *(const float4*)&det[((size_t)b * T_ + (t - 1)) * DET_ + j0];

    float4 ho;
    {
        float r, z, n;
        r = sigm(gr.x + br1.x + br2.x); z = sigm(gz.x + bz1.x + bz2.x);
        n = tanh_fast(gxn.x + bn1.x + r * (ghn.x + bn2.x)); ho.x = (1.f - z) * n + z * hp.x;
        r = sigm(gr.y + br1.y + br2.y); z = sigm(gz.y + bz1.y + bz2.y);
        n = tanh_fast(gxn.y + bn1.y + r * (ghn.y + bn2.y)); ho.y = (1.f - z) * n + z * hp.y;
        r = sigm(gr.z + br1.z + br2.z); z = sigm(gz.z + bz1.z + bz2.z);
        n = tanh_fast(gxn.z + bn1.z + r * (ghn.z + bn2.z)); ho.z = (1.f - z) * n + z * hp.z;
        r = sigm(gr.w + br1.w + br2.w); z = sigm(gz.w + bz1.w + bz2.w);
        n = tanh_fast(gxn.w + bn1.w + r * (ghn.w + bn2.w)); ho.w = (1.f - z) * n + z * hp.w;
    }
    *(float4*)&det[((size_t)b * T_ + t) * DET_ + j0] = ho;
}

// ---------------------------------------------------------------------------
// rep1 GEMM, split-K x3: P[s][512][512] partials. grid (8,8,3), tile 64x64.
// A = [h | e] (fp32 -> bf16 staged), B = RW1b.
// ---------------------------------------------------------------------------
__global__ __launch_bounds__(256) void k_rep1(
    const float* __restrict__ det, const float* __restrict__ emb,
    const short* __restrict__ RW1b, float* __restrict__ P, int t)
{
    __shared__ __align__(16) short As[64][72];
    __shared__ __align__(16) short Bs[64][72];

    const int tid = threadIdx.x;
    const int lane = tid & 63, wave = tid >> 6;
    const int wm = wave & 1, wn = wave >> 1;
    const int q = lane >> 4, m16 = lane & 15;
    const int n0 = blockIdx.x * 64, b0 = blockIdx.y * 64, s = blockIdx.z;

    f32x4 acc[2][2] = {{{0,0,0,0},{0,0,0,0}},{{0,0,0,0},{0,0,0,0}}};
    const int sr = tid >> 2, sc = (tid & 3) * 16;

    for (int kc = 0; kc < 8; ++kc) {
        {
            const int b = b0 + sr;
            const float* src;
            if (s == 0)      src = det + ((size_t)b * T_ + t) * DET_ + kc * 64 + sc;
            else if (s == 1) src = emb + ((size_t)b * T_ + t) * EMB_ + kc * 64 + sc;
            else             src = emb + ((size_t)b * T_ + t) * EMB_ + 512 + kc * 64 + sc;
            short tmp[16] __attribute__((aligned(16)));
            #pragma unroll
            for (int v4 = 0; v4 < 4; ++v4) {
                float4 f = ((const float4*)src)[v4];
                tmp[v4 * 4 + 0] = f2bf(f.x); tmp[v4 * 4 + 1] = f2bf(f.y);
                tmp[v4 * 4 + 2] = f2bf(f.z); tmp[v4 * 4 + 3] = f2bf(f.w);
            }
            *(bhalf8*)&As[sr][sc]     = *(bhalf8*)&tmp[0];
            *(bhalf8*)&As[sr][sc + 8] = *(bhalf8*)&tmp[8];
        }
        {
            const short* src = RW1b + (size_t)(n0 + sr) * 1536 + s * 512 + kc * 64 + sc;
            *(bhalf8*)&Bs[sr][sc] = *(const bhalf8*)src;
            *(bhalf8*)&Bs[sr][sc + 8] = *(const bhalf8*)(src + 8);
        }
        __syncthreads();
        #pragma unroll
        for (int kk = 0; kk < 64; kk += 32) {
            bhalf8 av[2], bv[2];
            #pragma unroll
            for (int mi = 0; mi < 2; ++mi)
                av[mi] = *(const bhalf8*)&As[wm * 32 + mi * 16 + m16][kk + q * 8];
            #pragma unroll
            for (int ni = 0; ni < 2; ++ni)
                bv[ni] = *(const bhalf8*)&Bs[wn * 32 + ni * 16 + m16][kk + q * 8];
            #pragma unroll
            for (int mi = 0; mi < 2; ++mi)
                #pragma unroll
                for (int ni = 0; ni < 2; ++ni)
                    acc[mi][ni] = __builtin_amdgcn_mfma_f32_16x16x32_bf16(
                        av[mi], bv[ni], acc[mi][ni], 0, 0, 0);
        }
        __syncthreads();
    }
    float* Ps = P + (size_t)s * 262144;
    #pragma unroll
    for (int mi = 0; mi < 2; ++mi)
        #pragma unroll
        for (int ni = 0; ni < 2; ++ni)
            #pragma unroll
            for (int r = 0; r < 4; ++r) {
                int row = wm * 32 + mi * 16 + q * 4 + r;
                int col = wn * 32 + ni * 16 + m16;
                Ps[(size_t)(b0 + row) * 512 + n0 + col] = acc[mi][ni][r];
            }
}

// ---------------------------------------------------------------------------
// rep2: q1 = elu(P0+P1+P2+b1) (staged bf16); D = q1 @ RW2b.T; dist + rsample.
// grid 16 (32 batch rows each), tile 32(M) x 64(N), K=512.
// ---------------------------------------------------------------------------
__global__ __launch_bounds__(256) void k_rep2(
    const float* __restrict__ P, const float* __restrict__ rb1,
    const short* __restrict__ RW2b, const float* __restrict__ rb2,
    const float* __restrict__ noise, float* __restrict__ stoch,
    float* __restrict__ qm, float* __restrict__ qsd, int t)
{
    __shared__ __align__(16) short As[32][72];
    __shared__ __align__(16) short Bs[64][72];
    __shared__ float o2[32][68];

    const int tid = threadIdx.x;
    const int lane = tid & 63, wave = tid >> 6;
    const int wm = wave & 1, wn = wave >> 1;
    const int q = lane >> 4, m16 = lane & 15;
    const int b0 = blockIdx.x * 32;

    f32x4 acc[2] = {{0,0,0,0},{0,0,0,0}};
    const float* P0 = P;
    const float* P1 = P + 262144;
    const float* P2 = P + 524288;

    for (int kc = 0; kc < 8; ++kc) {
        {   // stage A: 32 rows x 64 cols; 8 thr/row x 8 cols
            const int r = tid >> 3, c0 = (tid & 7) * 8;
            const int b = b0 + r;
            short tmp[8] __attribute__((aligned(16)));
            #pragma unroll
            for (int v4 = 0; v4 < 2; ++v4) {
                int k = kc * 64 + c0 + v4 * 4;
                float4 p0 = *(const float4*)&P0[(size_t)b * 512 + k];
                float4 p1 = *(const float4*)&P1[(size_t)b * 512 + k];
                float4 p2 = *(const float4*)&P2[(size_t)b * 512 + k];
                float4 bb = *(const float4*)&rb1[k];
                tmp[v4 * 4 + 0] = f2bf(eluf(p0.x + p1.x + p2.x + bb.x));
                tmp[v4 * 4 + 1] = f2bf(eluf(p0.y + p1.y + p2.y + bb.y));
                tmp[v4 * 4 + 2] = f2bf(eluf(p0.z + p1.z + p2.z + bb.z));
                tmp[v4 * 4 + 3] = f2bf(eluf(p0.w + p1.w + p2.w + bb.w));
            }
            *(bhalf8*)&As[r][c0] = *(bhalf8*)&tmp[0];
        }
        {   // stage B: 64 rows x 64 cols
            const int r = tid >> 2, c0 = (tid & 3) * 16;
            const short* src = RW2b + (size_t)r * 512 + kc * 64 + c0;
            *(bhalf8*)&Bs[r][c0] = *(const bhalf8*)src;
            *(bhalf8*)&Bs[r][c0 + 8] = *(const bhalf8*)(src + 8);
        }
        __syncthreads();
        #pragma unroll
        for (int kk = 0; kk < 64; kk += 32) {
            bhalf8 av = *(const bhalf8*)&As[wm * 16 + m16][kk + q * 8];
            bhalf8 bv[2];
            #pragma unroll
            for (int ni = 0; ni < 2; ++ni)
                bv[ni] = *(const bhalf8*)&Bs[wn * 32 + ni * 16 + m16][kk + q * 8];
            #pragma unroll
            for (int ni = 0; ni < 2; ++ni)
                acc[ni] = __builtin_amdgcn_mfma_f32_16x16x32_bf16(av, bv[ni], acc[ni], 0, 0, 0);
        }
        __syncthreads();
    }
    #pragma unroll
    for (int ni = 0; ni < 2; ++ni)
        #pragma unroll
        for (int r = 0; r < 4; ++r) {
            int row = wm * 16 + q * 4 + r;
            int col = wn * 32 + ni * 16 + m16;
            o2[row][col] = acc[ni][r] + rb2[col];
        }
    __syncthreads();
    {
        const int r = tid >> 3, c0 = (tid & 7) * 4;
        const int b = b0 + r;
        size_t base = ((size_t)b * T_ + t) * STOCH_ + c0;
        float4 nz = *(const float4*)&noise[base];
        float4 m, sd, st;
        m.x = o2[r][c0];     m.y = o2[r][c0 + 1]; m.z = o2[r][c0 + 2]; m.w = o2[r][c0 + 3];
        sd.x = softplusf(o2[r][32 + c0])     + 0.1f;
        sd.y = softplusf(o2[r][32 + c0 + 1]) + 0.1f;
        sd.z = softplusf(o2[r][32 + c0 + 2]) + 0.1f;
        sd.w = softplusf(o2[r][32 + c0 + 3]) + 0.1f;
        st.x = m.x + sd.x * nz.x; st.y = m.y + sd.y * nz.y;
        st.z = m.z + sd.z * nz.z; st.w = m.w + sd.w * nz.w;
        *(float4*)&qm[base] = m;
        *(float4*)&qsd[base] = sd;
        *(float4*)&stoch[base] = st;
    }
}

// ---------------------------------------------------------------------------
// Kernel: deferred transition MLP over all B*T rows (round-1, VALU+bf16 LDS).
// ---------------------------------------------------------------------------
__global__ __launch_bounds__(256) void k_trans(
    const float* __restrict__ det,
    const float* __restrict__ tw1, const float* __restrict__ tb1,
    const float* __restrict__ tw2, const float* __restrict__ tb2,
    float* __restrict__ pm, float* __restrict__ ps)
{
    __shared__ __hip_bfloat16 act[16][520];
    __shared__ __hip_bfloat16 t1h[16][520];
    __shared__ float wt[64][68];

    const int tid = threadIdx.x;
    const int row0 = blockIdx.x * 16;
    const int jc = tid & 63, rg = tid >> 6;

    for (int idx = tid; idx < 16 * 512; idx += 256) {
        int row = idx >> 9, k = idx & 511;
        act[row][k] = __float2bfloat16(det[(size_t)(row0 + row) * 512 + k]);
    }

    for (int c = 0; c < 8; ++c) {
        float acc[4] = {0,0,0,0};
        for (int kc = 0; kc < 8; ++kc) {
            const int k0 = kc * 64;
            __syncthreads();
            for (int idx = tid; idx < 64 * 64; idx += 256) {
                int row = idx >> 6, k = idx & 63;
                wt[row][k] = tw1[(size_t)(c * 64 + row) * 512 + k0 + k];
            }
            __syncthreads();
            for (int k = 0; k < 64; k += 4) {
                float4 wv = *(const float4*)&wt[jc][k];
                #pragma unroll
                for (int i = 0; i < 4; ++i) {
                    float a0, a1, a2, a3;
                    ld_bf16x4(&act[rg + 4 * i][k0 + k], a0, a1, a2, a3);
                    acc[i] += a0 * wv.x + a1 * wv.y + a2 * wv.z + a3 * wv.w;
                }
            }
        }
        #pragma unroll
        for (int i = 0; i < 4; ++i)
            t1h[rg + 4 * i][c * 64 + jc] = __float2bfloat16(eluf(acc[i] + tb1[c * 64 + jc]));
    }

    float acc2[4] = {0,0,0,0};
    for (int kc = 0; kc < 8; ++kc) {
        const int k0 = kc * 64;
        __syncthreads();
        for (int idx = tid; idx < 64 * 64; idx += 256) {
            int row = idx >> 6, k = idx & 63;
            wt[row][k] = tw2[(size_t)row * 512 + k0 + k];
        }
        __syncthreads();
        for (int k = 0; k < 64; k += 4) {
            float4 wv = *(const float4*)&wt[jc][k];
            #pragma unroll
            for (int i = 0; i < 4; ++i) {
                float a0, a1, a2, a3;
                ld_bf16x4(&t1h[rg + 4 * i][k0 + k], a0, a1, a2, a3);
                acc2[i] += a0 * wv.x + a1 * wv.y + a2 * wv.z + a3 * wv.w;
            }
        }
    }
    #pragma unroll
    for (int i = 0; i < 4; ++i) {
        size_t rgl = (size_t)row0 + rg + 4 * i;
        float v = acc2[i] + tb2[jc];
        if (jc < 32) pm[rgl * 32 + jc] = v;
        else         ps[rgl * 32 + (jc - 32)] = softplusf(v) + 0.1f;
    }
}

// ---------------------------------------------------------------------------
extern "C" void kernel_launch(void* const* d_in, const int* in_sizes, int n_in,
                              void* d_out, int out_size, void* d_ws, size_t ws_size,
                              hipStream_t stream) {
    const float* emb   = (const float*)d_in[0];
    const float* acts  = (const float*)d_in[1];
    const float* noise = (const float*)d_in[2];
    const float* wih   = (const float*)d_in[3];
    const float* whh   = (const float*)d_in[4];
    const float* bih   = (const float*)d_in[5];
    const float* bhh   = (const float*)d_in[6];
    const float* tw1   = (const float*)d_in[7];
    const float* tb1   = (const float*)d_in[8];
    const float* tw2   = (const float*)d_in[9];
    const float* tb2   = (const float*)d_in[10];
    const float* rw1   = (const float*)d_in[11];
    const float* rb1   = (const float*)d_in[12];
    const float* rw2   = (const float*)d_in[13];
    const float* rb2   = (const float*)d_in[14];

    float* out   = (float*)d_out;
    float* det   = out;
    float* stoch = out + OFF_STOCH;
    float* pm    = out + OFF_PM;
    float* ps    = out + OFF_PS;
    float* qm    = out + OFF_QM;
    float* qsd   = out + OFF_QS;

    // scratch carved from pm/ps slices (trans overwrites them at the end)
    float* G  = pm;                     // [512][2048] fp32
    float* P  = pm + 1048576;           // 3 x [512][512] fp32 partials
    short* WBIG = (short*)ps;           // [2048][576] bf16
    short* RW1b = WBIG + 2048 * 576;    // [512][1536] bf16
    short* RW2b = RW1b + 512 * 1536;    // [64][512] bf16

    k_prep<<<dim3(1024), 256, 0, stream>>>(wih, whh, rw1, rw2, WBIG, RW1b, RW2b);

    for (int t = 0; t < T_; ++t) {
        k_gemm_gru<<<dim3(32, 8), 256, 0, stream>>>(det, stoch, acts, WBIG, G, t);
        k_gate<<<dim3(256), 256, 0, stream>>>(G, bih, bhh, det, t);
        k_rep1<<<dim3(8, 8, 3), 256, 0, stream>>>(det, emb, RW1b, P, t);
        k_rep2<<<dim3(16), 256, 0, stream>>>(P, rb1, RW2b, rb2, noise, stoch, qm, qsd, t);
    }
    k_trans<<<dim3(4096), 256, 0, stream>>>(det, tw1, tb1, tw2, tb2, pm, ps);
}

// Round 3
// 23288.571 us; speedup vs baseline: 2.5612x; 1.1704x over previous
//
#include <hip/hip_runtime.h>
#include <hip/hip_bf16.h>
#include <math.h>

#define B_    512
#define T_    128
#define DET_  512
#define STOCH_ 32
#define EMB_  1024
#define ACTD_ 6
#define HID_  512

// output slice offsets (floats)
#define OFF_STOCH 33554432u
#define OFF_PM    35651584u
#define OFF_PS    37748736u
#define OFF_QM    39845888u
#define OFF_QS    41943040u

typedef short bhalf8 __attribute__((ext_vector_type(8)));
typedef float f32x4  __attribute__((ext_vector_type(4)));

__device__ __forceinline__ float sigm(float x) { return 1.f / (1.f + __expf(-x)); }
__device__ __forceinline__ float softplusf(float x) {
    return fmaxf(x, 0.f) + log1pf(__expf(-fabsf(x)));
}
__device__ __forceinline__ float eluf(float x) { return (x > 0.f) ? x : (__expf(x) - 1.f); }
__device__ __forceinline__ float tanh_fast(float x) {
    return 1.f - 2.f / (__expf(2.f * x) + 1.f);
}
__device__ __forceinline__ short f2bf(float f) {
    __hip_bfloat16 h = __float2bfloat16(f);
    return *reinterpret_cast<short*>(&h);
}
__device__ __forceinline__ void pack4(short* dst, float4 f) {
    dst[0] = f2bf(f.x); dst[1] = f2bf(f.y); dst[2] = f2bf(f.z); dst[3] = f2bf(f.w);
}

// ---------------------------------------------------------------------------
// Prep: bf16 weight images in the ps output slice (scratch until k_trans runs).
//   WBIG [2048][576]: rows 0..511 r [wih_r|whh_r], 512..1023 z, 1024..1535 hn
//   [0|whh_n], 1536..2047 xn [wih_n|0]. K: k<64 = [s(32),a(6),0(26)], k>=64 = h.
// ---------------------------------------------------------------------------
__global__ __launch_bounds__(256) void k_prep(
    const float* __restrict__ wih, const float* __restrict__ whh,
    const float* __restrict__ rw1, const float* __restrict__ rw2,
    short* __restrict__ WBIG, short* __restrict__ RW1b, short* __restrict__ RW2b)
{
    const int idx = blockIdx.x * 256 + threadIdx.x;
    const int stride = gridDim.x * 256;
    for (int i = idx; i < 2048 * 576; i += stride) {
        int n = i / 576, k = i - n * 576;
        float v = 0.f;
        if (k < 64) {
            if (k < 38) {
                if (n < 1024)       v = wih[n * 38 + k];
                else if (n >= 1536) v = wih[(n - 512) * 38 + k];
            }
        } else {
            if (n < 1536) v = whh[(size_t)n * 512 + (k - 64)];
        }
        WBIG[i] = f2bf(v);
    }
    for (int i = idx; i < 512 * 1536; i += stride) RW1b[i] = f2bf(rw1[i]);
    for (int i = idx; i < 64 * 512; i += stride)   RW2b[i] = f2bf(rw2[i]);
}

// ---------------------------------------------------------------------------
// Persistent scan: 32 WGs x 256 thr; WG owns 16 batch rows for all 128 steps.
// h_prev in registers, s/h/e/q1 staged in LDS, weights streamed from L2.
// Waves split the N dimension (wave w owns cols w*128..w*128+127).
// ---------------------------------------------------------------------------
__global__ __launch_bounds__(256, 1) void k_scan(
    const float* __restrict__ emb, const float* __restrict__ actions,
    const float* __restrict__ noise,
    const short* __restrict__ WBIG, const short* __restrict__ RW1b,
    const short* __restrict__ RW2b,
    const float* __restrict__ bih, const float* __restrict__ bhh,
    const float* __restrict__ rb1, const float* __restrict__ rb2,
    float* __restrict__ det, float* __restrict__ stoch,
    float* __restrict__ qm, float* __restrict__ qsd)
{
    __shared__ __align__(16) short gruA[16][584];   // [s|a|pad|h] bf16, col==K of WBIG
    __shared__ __align__(16) short repA[16][1544];  // [h|e] bf16
    __shared__ __align__(16) short q1A[16][520];    // q1 bf16
    __shared__ float o2[16][68];                    // rep2 out fp32

    const int tid = threadIdx.x;
    const int lane = tid & 63, w = tid >> 6;
    const int q = lane >> 4, m16 = lane & 15;
    const int b0 = blockIdx.x * 16;
    const f32x4 zero4 = {0.f, 0.f, 0.f, 0.f};

    // ---- prologue ----
    for (int i = tid; i < 16 * 584; i += 256) ((short*)gruA)[i] = 0;
    if (tid < 96) {
        int row = tid / 6, k = tid - row * 6;
        gruA[row][32 + k] = f2bf(actions[((size_t)(b0 + row) * T_) * ACTD_ + k]);
    }
    float brg[8], bzg[8], bnxg[8], bnhg[8], rb1g[8];
    #pragma unroll
    for (int ti = 0; ti < 8; ++ti) {
        int j = w * 128 + ti * 16 + m16;
        brg[ti]  = bih[j] + bhh[j];
        bzg[ti]  = bih[512 + j] + bhh[512 + j];
        bnxg[ti] = bih[1024 + j];
        bnhg[ti] = bhh[1024 + j];
        rb1g[ti] = rb1[j];
    }
    const float rb2g = rb2[w * 16 + m16];
    float hprev[8][4];
    #pragma unroll
    for (int ti = 0; ti < 8; ++ti)
        #pragma unroll
        for (int rr = 0; rr < 4; ++rr) hprev[ti][rr] = 0.f;
    __syncthreads();

    for (int t = 0; t < T_; ++t) {
        // ---- Phase E: stage e_t (fp32 -> bf16) into repA[.][512..1535] ----
        #pragma unroll
        for (int u = 0; u < 4; ++u) {
            int row = w * 4 + u;
            const float* src = emb + ((size_t)(b0 + row) * T_ + t) * EMB_ + lane * 16;
            float4 f0 = ((const float4*)src)[0];
            float4 f1 = ((const float4*)src)[1];
            float4 f2 = ((const float4*)src)[2];
            float4 f3 = ((const float4*)src)[3];
            short tmp[16] __attribute__((aligned(16)));
            pack4(&tmp[0], f0); pack4(&tmp[4], f1);
            pack4(&tmp[8], f2); pack4(&tmp[12], f3);
            *(bhalf8*)&repA[row][512 + lane * 16]     = *(bhalf8*)&tmp[0];
            *(bhalf8*)&repA[row][512 + lane * 16 + 8] = *(bhalf8*)&tmp[8];
        }

        // ---- Phase G: GRU GEMM (gruA x WBIG) ----
        f32x4 aR[8], aZ[8], aN[8], aX[8];
        #pragma unroll
        for (int ti = 0; ti < 8; ++ti) { aR[ti] = zero4; aZ[ti] = zero4; aN[ti] = zero4; aX[ti] = zero4; }

        #pragma unroll 2
        for (int kt = 0; kt < 18; ++kt) {
            const int k0 = kt * 32;
            bhalf8 af = *(const bhalf8*)&gruA[m16][k0 + q * 8];
            const int n3base = (kt < 2) ? 1536 : 1024;
            #pragma unroll
            for (int ti = 0; ti < 8; ++ti) {
                const int nr = w * 128 + ti * 16 + m16;
                bhalf8 bR = *(const bhalf8*)&WBIG[(size_t)nr * 576 + k0 + q * 8];
                bhalf8 bZ = *(const bhalf8*)&WBIG[(size_t)(512 + nr) * 576 + k0 + q * 8];
                bhalf8 bN = *(const bhalf8*)&WBIG[(size_t)(n3base + nr) * 576 + k0 + q * 8];
                aR[ti] = __builtin_amdgcn_mfma_f32_16x16x32_bf16(af, bR, aR[ti], 0, 0, 0);
                aZ[ti] = __builtin_amdgcn_mfma_f32_16x16x32_bf16(af, bZ, aZ[ti], 0, 0, 0);
                if (kt < 2) aX[ti] = __builtin_amdgcn_mfma_f32_16x16x32_bf16(af, bN, aX[ti], 0, 0, 0);
                else        aN[ti] = __builtin_amdgcn_mfma_f32_16x16x32_bf16(af, bN, aN[ti], 0, 0, 0);
            }
        }

        // ---- gate epilogue: h in regs; write det + repA h now, gruA h after barrier ----
        #pragma unroll
        for (int ti = 0; ti < 8; ++ti) {
            const int j = w * 128 + ti * 16 + m16;
            #pragma unroll
            for (int rr = 0; rr < 4; ++rr) {
                float r = sigm(aR[ti][rr] + brg[ti]);
                float z = sigm(aZ[ti][rr] + bzg[ti]);
                float n = tanh_fast(aX[ti][rr] + bnxg[ti] + r * (aN[ti][rr] + bnhg[ti]));
                float h = (1.f - z) * n + z * hprev[ti][rr];
                hprev[ti][rr] = h;
                det[((size_t)(b0 + q * 4 + rr) * T_ + t) * DET_ + j] = h;
                repA[q * 4 + rr][j] = f2bf(h);
            }
        }
        __syncthreads();   // (1) all GRU reads of gruA done; repA h/e complete
        #pragma unroll
        for (int ti = 0; ti < 8; ++ti) {
            const int j = w * 128 + ti * 16 + m16;
            #pragma unroll
            for (int rr = 0; rr < 4; ++rr)
                gruA[q * 4 + rr][64 + j] = f2bf(hprev[ti][rr]);
        }

        // ---- Phase R1: rep1 GEMM (repA x RW1b) ----
        f32x4 a1[8];
        #pragma unroll
        for (int ti = 0; ti < 8; ++ti) a1[ti] = zero4;
        #pragma unroll 2
        for (int kt = 0; kt < 48; ++kt) {
            const int k0 = kt * 32;
            bhalf8 af = *(const bhalf8*)&repA[m16][k0 + q * 8];
            #pragma unroll
            for (int ti = 0; ti < 8; ++ti) {
                const int nr = w * 128 + ti * 16 + m16;
                bhalf8 bv = *(const bhalf8*)&RW1b[(size_t)nr * 1536 + k0 + q * 8];
                a1[ti] = __builtin_amdgcn_mfma_f32_16x16x32_bf16(af, bv, a1[ti], 0, 0, 0);
            }
        }
        #pragma unroll
        for (int ti = 0; ti < 8; ++ti) {
            const int j = w * 128 + ti * 16 + m16;
            #pragma unroll
            for (int rr = 0; rr < 4; ++rr)
                q1A[q * 4 + rr][j] = f2bf(eluf(a1[ti][rr] + rb1g[ti]));
        }
        __syncthreads();   // (2)

        // ---- Phase R2: rep2 GEMM (q1A x RW2b), N=64 split 16/wave ----
        f32x4 a2 = zero4;
        #pragma unroll 2
        for (int kt = 0; kt < 16; ++kt) {
            const int k0 = kt * 32;
            bhalf8 af = *(const bhalf8*)&q1A[m16][k0 + q * 8];
            bhalf8 bv = *(const bhalf8*)&RW2b[(size_t)(w * 16 + m16) * 512 + k0 + q * 8];
            a2 = __builtin_amdgcn_mfma_f32_16x16x32_bf16(af, bv, a2, 0, 0, 0);
        }
        #pragma unroll
        for (int rr = 0; rr < 4; ++rr)
            o2[q * 4 + rr][w * 16 + m16] = a2[rr] + rb2g;
        __syncthreads();   // (3)

        // ---- sample: qm/qs/stoch out, s -> gruA, a_{t+1} -> gruA ----
        {
            const int row = tid >> 4, c = (tid & 15) * 2;
            float m0 = o2[row][c], m1 = o2[row][c + 1];
            float s0 = softplusf(o2[row][c + 32]) + 0.1f;
            float s1 = softplusf(o2[row][c + 33]) + 0.1f;
            size_t base = ((size_t)(b0 + row) * T_ + t) * STOCH_ + c;
            float2 nz = *(const float2*)&noise[base];
            float st0 = m0 + s0 * nz.x, st1 = m1 + s1 * nz.y;
            *(float2*)&qm[base]    = make_float2(m0, m1);
            *(float2*)&qsd[base]   = make_float2(s0, s1);
            *(float2*)&stoch[base] = make_float2(st0, st1);
            short2 sp; sp.x = f2bf(st0); sp.y = f2bf(st1);
            *(short2*)&gruA[row][c] = sp;
        }
        if (t + 1 < T_ && tid < 96) {
            int row = tid / 6, k = tid - row * 6;
            gruA[row][32 + k] = f2bf(actions[((size_t)(b0 + row) * T_ + (t + 1)) * ACTD_ + k]);
        }
        __syncthreads();   // (4)
    }
}

// ---------------------------------------------------------------------------
// Trans MLP, MFMA, fused 2 layers. M=64/WG, grid 1024, 4 waves split N.
// Single LDS buffer: A (det bf16) then overwritten by t1 after barrier.
// ---------------------------------------------------------------------------
__global__ __launch_bounds__(256, 2) void k_trans(
    const float* __restrict__ det,
    const float* __restrict__ tw1, const float* __restrict__ tb1,
    const float* __restrict__ tw2, const float* __restrict__ tb2,
    float* __restrict__ pm, float* __restrict__ ps)
{
    __shared__ __align__(16) short buf[64][520];
    const int tid = threadIdx.x;
    const int lane = tid & 63, w = tid >> 6;
    const int q = lane >> 4, m16 = lane & 15;
    const size_t row0 = (size_t)blockIdx.x * 64;

    // stage A: 64 rows x 512 fp32 -> bf16 (4 thr/row x 128 cols)
    {
        const int row = tid >> 2, c0 = (tid & 3) * 128;
        const float* src = det + (row0 + row) * 512 + c0;
        #pragma unroll
        for (int v = 0; v < 8; ++v) {
            float4 f0 = ((const float4*)src)[v * 4 + 0];
            float4 f1 = ((const float4*)src)[v * 4 + 1];
            float4 f2 = ((const float4*)src)[v * 4 + 2];
            float4 f3 = ((const float4*)src)[v * 4 + 3];
            short tmp[16] __attribute__((aligned(16)));
            pack4(&tmp[0], f0); pack4(&tmp[4], f1);
            pack4(&tmp[8], f2); pack4(&tmp[12], f3);
            *(bhalf8*)&buf[row][c0 + v * 16]     = *(bhalf8*)&tmp[0];
            *(bhalf8*)&buf[row][c0 + v * 16 + 8] = *(bhalf8*)&tmp[8];
        }
    }
    __syncthreads();

    float tb1g[8];
    #pragma unroll
    for (int ti = 0; ti < 8; ++ti) tb1g[ti] = tb1[w * 128 + ti * 16 + m16];

    // layer 1: wave w cols w*128..+127, 4 M-tiles, K=512
    f32x4 acc[4][8];
    #pragma unroll
    for (int mt = 0; mt < 4; ++mt)
        #pragma unroll
        for (int ti = 0; ti < 8; ++ti) acc[mt][ti] = (f32x4){0.f, 0.f, 0.f, 0.f};

    #pragma unroll 2
    for (int kt = 0; kt < 16; ++kt) {
        const int k0 = kt * 32;
        bhalf8 af[4];
        #pragma unroll
        for (int mt = 0; mt < 4; ++mt)
            af[mt] = *(const bhalf8*)&buf[mt * 16 + m16][k0 + q * 8];
        #pragma unroll
        for (int ti = 0; ti < 8; ++ti) {
            const int nr = w * 128 + ti * 16 + m16;
            const float* bsrc = tw1 + (size_t)nr * 512 + k0 + q * 8;
            float4 g0 = ((const float4*)bsrc)[0];
            float4 g1 = ((const float4*)bsrc)[1];
            short bt[8] __attribute__((aligned(16)));
            pack4(&bt[0], g0); pack4(&bt[4], g1);
            bhalf8 bv = *(bhalf8*)&bt[0];
            #pragma unroll
            for (int mt = 0; mt < 4; ++mt)
                acc[mt][ti] = __builtin_amdgcn_mfma_f32_16x16x32_bf16(af[mt], bv, acc[mt][ti], 0, 0, 0);
        }
    }
    __syncthreads();   // all A reads done; buf becomes t1
    #pragma unroll
    for (int mt = 0; mt < 4; ++mt)
        #pragma unroll
        for (int ti = 0; ti < 8; ++ti) {
            const int j = w * 128 + ti * 16 + m16;
            #pragma unroll
            for (int rr = 0; rr < 4; ++rr)
                buf[mt * 16 + q * 4 + rr][j] = f2bf(eluf(acc[mt][ti][rr] + tb1g[ti]));
        }
    __syncthreads();

    // layer 2: wave w owns out cols w*16..+15 (N=64 total), K=512
    const float tb2g = tb2[w * 16 + m16];
    f32x4 a2[4];
    #pragma unroll
    for (int mt = 0; mt < 4; ++mt) a2[mt] = (f32x4){0.f, 0.f, 0.f, 0.f};
    #pragma unroll 2
    for (int kt = 0; kt < 16; ++kt) {
        const int k0 = kt * 32;
        const float* bsrc = tw2 + (size_t)(w * 16 + m16) * 512 + k0 + q * 8;
        float4 g0 = ((const float4*)bsrc)[0];
        float4 g1 = ((const float4*)bsrc)[1];
        short bt[8] __attribute__((aligned(16)));
        pack4(&bt[0], g0); pack4(&bt[4], g1);
        bhalf8 bv = *(bhalf8*)&bt[0];
        #pragma unroll
        for (int mt = 0; mt < 4; ++mt) {
            bhalf8 af = *(const bhalf8*)&buf[mt * 16 + m16][k0 + q * 8];
            a2[mt] = __builtin_amdgcn_mfma_f32_16x16x32_bf16(af, bv, a2[mt], 0, 0, 0);
        }
    }
    const int j2 = w * 16 + m16;
    #pragma unroll
    for (int mt = 0; mt < 4; ++mt)
        #pragma unroll
        for (int rr = 0; rr < 4; ++rr) {
            size_t R = row0 + mt * 16 + q * 4 + rr;
            float v = a2[mt][rr] + tb2g;
            if (j2 < 32) pm[R * 32 + j2] = v;
            else         ps[R * 32 + (j2 - 32)] = softplusf(v) + 0.1f;
        }
}

// ---------------------------------------------------------------------------
extern "C" void kernel_launch(void* const* d_in, const int* in_sizes, int n_in,
                              void* d_out, int out_size, void* d_ws, size_t ws_size,
                              hipStream_t stream) {
    const float* emb   = (const float*)d_in[0];
    const float* acts  = (const float*)d_in[1];
    const float* noise = (const float*)d_in[2];
    const float* wih   = (const float*)d_in[3];
    const float* whh   = (const float*)d_in[4];
    const float* bih   = (const float*)d_in[5];
    const float* bhh   = (const float*)d_in[6];
    const float* tw1   = (const float*)d_in[7];
    const float* tb1   = (const float*)d_in[8];
    const float* tw2   = (const float*)d_in[9];
    const float* tb2   = (const float*)d_in[10];
    const float* rw1   = (const float*)d_in[11];
    const float* rb1   = (const float*)d_in[12];
    const float* rw2   = (const float*)d_in[13];
    const float* rb2   = (const float*)d_in[14];

    float* out   = (float*)d_out;
    float* det   = out;
    float* stoch = out + OFF_STOCH;
    float* pm    = out + OFF_PM;
    float* ps    = out + OFF_PS;
    float* qm    = out + OFF_QM;
    float* qsd   = out + OFF_QS;

    // bf16 weight scratch lives in the ps slice; k_trans (the only writer of
    // ps) runs after the scan kernel has fully consumed these. 2.0M shorts
    // fit in ps's 2.1M floats.
    short* WBIG = (short*)ps;           // [2048][576]
    short* RW1b = WBIG + 2048 * 576;    // [512][1536]
    short* RW2b = RW1b + 512 * 1536;    // [64][512]

    k_prep<<<dim3(1024), 256, 0, stream>>>(wih, whh, rw1, rw2, WBIG, RW1b, RW2b);
    k_scan<<<dim3(32), 256, 0, stream>>>(emb, acts, noise, WBIG, RW1b, RW2b,
                                         bih, bhh, rb1, rb2, det, stoch, qm, qsd);
    k_trans<<<dim3(1024), 256, 0, stream>>>(det, tw1, tb1, tw2, tb2, pm, ps);
}